// Round 3
// baseline (4860.594 us; speedup 1.0000x reference)
//
#include <hip/hip_runtime.h>
#include <math.h>

#define V 64
#define TMAX 2048
#define ED 512
#define H 64
#define G3 192
#define BT 128
#define BG 96

typedef const __attribute__((address_space(1))) void gvoid;
typedef __attribute__((address_space(3))) void lvoid;

// ---------------- K0: zero the persistent hidden state ----------------
__global__ void k_init(float* __restrict__ h) {
    int i = blockIdx.x * blockDim.x + threadIdx.x;
    if (i < V * H) h[i] = 0.f;
}

// ---------------- K1: xg[v, tloc, g] = b_ih[g] + sum_k emb[v,t,k] * W_ih[g,k]
// Block tile 128t x 96g (g split over 2 blocks), thread tile 8t x 6g, K chunk 32.
// Staging via global_load_lds width=16. LDS row = 32 floats, k-groups XOR-swizzled
// by (row>>3)&7 on the GLOBAL address side so compute reads are <=2-way banked.
__global__ __launch_bounds__(256, 2) void k_gemm(
    const float* __restrict__ emb, const int* __restrict__ lengths,
    const float* __restrict__ W_ih, const float* __restrict__ b_ih,
    float* __restrict__ xg, int c, int CT) {
    int v = blockIdx.z;
    int tile0 = blockIdx.x * BT;
    int gbase = blockIdx.y * BG;
    if (c * CT + tile0 >= lengths[v]) return;  // tile never read downstream

    __shared__ __align__(16) float Es[BT][32];
    __shared__ __align__(16) float Ws[BG][32];

    int th = threadIdx.x;
    int wv = th >> 6;    // wave 0..3
    int l  = th & 63;    // lane
    int tq = th & 15;    // t-group: rows tq*8..tq*8+7
    int gq = th >> 4;    // g-group: rows gq*6..gq*6+5
    int lrow  = l >> 3;  // staging: row within 8-row group
    int jslot = l & 7;   // staging: LDS k4 slot

    const float* ebase = emb + ((size_t)v * TMAX + c * CT + tile0) * ED;
    const float* wbase = W_ih + (size_t)gbase * ED;

    float acc[8][6];
#pragma unroll
    for (int i = 0; i < 8; i++)
#pragma unroll
        for (int j = 0; j < 6; j++) acc[i][j] = 0.f;

    for (int kc = 0; kc < ED; kc += 32) {
        // E tile: wave wv stages rows [wv*32, wv*32+32) as 4 instrs of 8 rows
#pragma unroll
        for (int m = 0; m < 4; m++) {
            int r0 = wv * 32 + m * 8;
            int kg = (jslot ^ ((r0 >> 3) & 7)) & 7;
            __builtin_amdgcn_global_load_lds(
                (gvoid*)(ebase + (size_t)(r0 + lrow) * ED + kc + kg * 4),
                (lvoid*)&Es[r0][0], 16, 0, 0);
        }
        // W tile: wave wv stages rows [wv*24, wv*24+24) as 3 instrs of 8 rows
#pragma unroll
        for (int m = 0; m < 3; m++) {
            int r0 = wv * 24 + m * 8;
            int kg = (jslot ^ ((r0 >> 3) & 7)) & 7;
            __builtin_amdgcn_global_load_lds(
                (gvoid*)(wbase + (size_t)(r0 + lrow) * ED + kc + kg * 4),
                (lvoid*)&Ws[r0][0], 16, 0, 0);
        }
        __syncthreads();
#pragma unroll
        for (int k4 = 0; k4 < 8; k4++) {
            float4 e[8], w[6];
#pragma unroll
            for (int i = 0; i < 8; i++)
                e[i] = *(float4*)&Es[tq * 8 + i][((k4 ^ tq) & 7) * 4];
#pragma unroll
            for (int j = 0; j < 6; j++) {
                int row = gq * 6 + j;
                w[j] = *(float4*)&Ws[row][((k4 ^ (row >> 3)) & 7) * 4];
            }
#pragma unroll
            for (int i = 0; i < 8; i++)
#pragma unroll
                for (int j = 0; j < 6; j++)
                    acc[i][j] += e[i].x * w[j].x + e[i].y * w[j].y +
                                 e[i].z * w[j].z + e[i].w * w[j].w;
        }
        __syncthreads();
    }

    float bj[6];
#pragma unroll
    for (int j = 0; j < 6; j++) bj[j] = b_ih[gbase + gq * 6 + j];

    size_t base = ((size_t)v * CT + tile0 + tq * 8) * G3 + gbase + gq * 6;
#pragma unroll
    for (int i = 0; i < 8; i++) {
#pragma unroll
        for (int j2 = 0; j2 < 3; j2++) {
            float2 s;
            s.x = acc[i][j2 * 2 + 0] + bj[j2 * 2 + 0];
            s.y = acc[i][j2 * 2 + 1] + bj[j2 * 2 + 1];
            *(float2*)&xg[base + (size_t)i * G3 + j2 * 2] = s;
        }
    }
}

// ---------------- K2: GRU recurrence, ONE WAVE per var, zero barriers.
// Lane i holds W_hh rows i (r), 64+i (z), 128+i (n) in 192 VGPRs.
// h exchanged through LDS; ordering via in-order DS + wave_barrier (no s_barrier,
// so the 8-step-ahead xg prefetch is never vmcnt-drained).
__global__ __launch_bounds__(64, 1) void k_rec(
    const float* __restrict__ xg, const int* __restrict__ lengths,
    const float* __restrict__ W_hh, const float* __restrict__ b_hh,
    float* __restrict__ h, int c, int CT) {
    int v = blockIdx.x;
    int l = threadIdx.x;
    int len = lengths[v];
    int rem = len - c * CT;
    int tcnt = rem < 0 ? 0 : (rem > CT ? CT : rem);

    __shared__ __align__(16) float hs[H];
    __shared__ __align__(16) float xb[2][8 * G3];

    float4 wr[16], wz[16], wn[16];
#pragma unroll
    for (int k4 = 0; k4 < 16; k4++) {
        wr[k4] = *(const float4*)&W_hh[(size_t)l * H + k4 * 4];
        wz[k4] = *(const float4*)&W_hh[(size_t)(64 + l) * H + k4 * 4];
        wn[k4] = *(const float4*)&W_hh[(size_t)(128 + l) * H + k4 * 4];
    }
    float br = b_hh[l], bz = b_hh[64 + l], bn = b_hh[128 + l];

    float hp = h[v * H + l];
    hs[l] = hp;

    const float* xgv = xg + (size_t)v * CT * G3;
    float4 pf[6];
#pragma unroll
    for (int p = 0; p < 6; p++) pf[p].x = pf[p].y = pf[p].z = pf[p].w = 0.f;

    if (tcnt > 0) {
#pragma unroll
        for (int p = 0; p < 6; p++) {
            float4 t4 = *(const float4*)&xgv[p * 256 + l * 4];
            *(float4*)&xb[0][p * 256 + l * 4] = t4;
        }
        if (tcnt > 8) {
#pragma unroll
            for (int p = 0; p < 6; p++)
                pf[p] = *(const float4*)&xgv[1536 + p * 256 + l * 4];
        }
    }
    __builtin_amdgcn_wave_barrier();

    const float LOG2E = 1.4426950408889634f;

    for (int t = 0; t < tcnt; t++) {
        int tm = t & 7;
        if (tm == 0 && t) {
            int b = (t >> 3) & 1;
#pragma unroll
            for (int p = 0; p < 6; p++)
                *(float4*)&xb[b][p * 256 + l * 4] = pf[p];
            if (t + 8 < tcnt) {
#pragma unroll
                for (int p = 0; p < 6; p++)
                    pf[p] = *(const float4*)&xgv[(size_t)(t + 8) * G3 + p * 256 + l * 4];
            }
            __builtin_amdgcn_wave_barrier();
        }
        const float* xrow = &xb[(t >> 3) & 1][tm * G3];

        float ar0 = 0.f, ar1 = 0.f, ar2 = 0.f, ar3 = 0.f;
        float az0 = 0.f, az1 = 0.f, az2 = 0.f, az3 = 0.f;
        float an0 = 0.f, an1 = 0.f, an2 = 0.f, an3 = 0.f;
#pragma unroll
        for (int k4 = 0; k4 < 16; k4 += 4) {
            float4 h0 = *(float4*)&hs[k4 * 4];
            float4 h1 = *(float4*)&hs[k4 * 4 + 4];
            float4 h2 = *(float4*)&hs[k4 * 4 + 8];
            float4 h3 = *(float4*)&hs[k4 * 4 + 12];
            ar0 += wr[k4].x * h0.x + wr[k4].y * h0.y + wr[k4].z * h0.z + wr[k4].w * h0.w;
            ar1 += wr[k4+1].x * h1.x + wr[k4+1].y * h1.y + wr[k4+1].z * h1.z + wr[k4+1].w * h1.w;
            ar2 += wr[k4+2].x * h2.x + wr[k4+2].y * h2.y + wr[k4+2].z * h2.z + wr[k4+2].w * h2.w;
            ar3 += wr[k4+3].x * h3.x + wr[k4+3].y * h3.y + wr[k4+3].z * h3.z + wr[k4+3].w * h3.w;
            az0 += wz[k4].x * h0.x + wz[k4].y * h0.y + wz[k4].z * h0.z + wz[k4].w * h0.w;
            az1 += wz[k4+1].x * h1.x + wz[k4+1].y * h1.y + wz[k4+1].z * h1.z + wz[k4+1].w * h1.w;
            az2 += wz[k4+2].x * h2.x + wz[k4+2].y * h2.y + wz[k4+2].z * h2.z + wz[k4+2].w * h2.w;
            az3 += wz[k4+3].x * h3.x + wz[k4+3].y * h3.y + wz[k4+3].z * h3.z + wz[k4+3].w * h3.w;
            an0 += wn[k4].x * h0.x + wn[k4].y * h0.y + wn[k4].z * h0.z + wn[k4].w * h0.w;
            an1 += wn[k4+1].x * h1.x + wn[k4+1].y * h1.y + wn[k4+1].z * h1.z + wn[k4+1].w * h1.w;
            an2 += wn[k4+2].x * h2.x + wn[k4+2].y * h2.y + wn[k4+2].z * h2.z + wn[k4+2].w * h2.w;
            an3 += wn[k4+3].x * h3.x + wn[k4+3].y * h3.y + wn[k4+3].z * h3.z + wn[k4+3].w * h3.w;
        }
        float ar = ((ar0 + ar1) + (ar2 + ar3)) + br;
        float az = ((az0 + az1) + (az2 + az3)) + bz;
        float an = ((an0 + an1) + (an2 + an3)) + bn;

        float r = __builtin_amdgcn_rcpf(1.f + __builtin_amdgcn_exp2f(-LOG2E * (ar + xrow[l])));
        float z = __builtin_amdgcn_rcpf(1.f + __builtin_amdgcn_exp2f(-LOG2E * (az + xrow[64 + l])));
        float targ = xrow[128 + l] + r * an;
        float e2 = __builtin_amdgcn_exp2f(-2.f * LOG2E * fabsf(targ));
        float tn = (1.f - e2) * __builtin_amdgcn_rcpf(1.f + e2);
        tn = __builtin_copysignf(tn, targ);
        hp = tn + z * (hp - tn);

        __builtin_amdgcn_wave_barrier();
        hs[l] = hp;
        __builtin_amdgcn_wave_barrier();
    }
    h[v * H + l] = hp;
}

// ---------------- K2F: fully-fused fallback (tiny workspace). Slow but correct.
__global__ __launch_bounds__(192) void k_rec_fused(
    const float* __restrict__ emb, const int* __restrict__ lengths,
    const float* __restrict__ W_ih, const float* __restrict__ b_ih,
    const float* __restrict__ W_hh, const float* __restrict__ b_hh,
    float* __restrict__ h) {
    int v = blockIdx.x;
    int th = threadIdx.x;
    int len = lengths[v];

    __shared__ __align__(16) float hs[H];
    __shared__ __align__(16) float es[ED];
    __shared__ float znbuf[128];
    __shared__ float xnbuf[64];

    float4 w4[16];
#pragma unroll
    for (int k4 = 0; k4 < 16; k4++)
        w4[k4] = *(const float4*)&W_hh[(size_t)th * H + k4 * 4];
    float bhh = b_hh[th];
    float bih = b_ih[th];
    if (th < H) hs[th] = 0.f;
    const float* ev = emb + (size_t)v * TMAX * ED;
    const float* wrow = W_ih + (size_t)th * ED;

    for (int t = 0; t < len; t++) {
        __syncthreads();
        for (int i = th; i < 128; i += 192)
            *(float4*)&es[i * 4] = *(const float4*)&ev[(size_t)t * ED + i * 4];
        __syncthreads();
        float xgt = bih;
        for (int k4 = 0; k4 < 128; k4++) {
            float4 wv = *(const float4*)&wrow[k4 * 4];
            float4 e4 = *(float4*)&es[k4 * 4];
            xgt += wv.x * e4.x + wv.y * e4.y + wv.z * e4.z + wv.w * e4.w;
        }
        float hg = bhh;
#pragma unroll
        for (int k4 = 0; k4 < 16; k4++) {
            float4 h4 = *(float4*)&hs[k4 * 4];
            hg += w4[k4].x * h4.x + w4[k4].y * h4.y + w4[k4].z * h4.z + w4[k4].w * h4.w;
        }
        if (th >= H && th < 128) znbuf[th - H] = hg + xgt;
        if (th >= 128) { znbuf[th - H] = hg; xnbuf[th - 128] = xgt; }
        __syncthreads();
        if (th < H) {
            float r = 1.f / (1.f + expf(-(hg + xgt)));
            float z = 1.f / (1.f + expf(-znbuf[th]));
            float n = tanhf(xnbuf[th] + r * znbuf[64 + th]);
            float hold = hs[th];
            hs[th] = (1.f - z) * n + z * hold;
        }
    }
    __syncthreads();
    if (th < H) h[v * H + th] = hs[th];
}

// ---------------- K3a: hid[o] = relu(b1[o] + W1[o,:] . concat)
__global__ __launch_bounds__(256) void k_mlp1(
    const float* __restrict__ h, const float* __restrict__ W1,
    const float* __restrict__ b1, float* __restrict__ hid) {
    int o = blockIdx.x, th = threadIdx.x;
    const float* w = W1 + (size_t)o * (V * H);
    float s = 0.f;
#pragma unroll
    for (int r = 0; r < 4; r++) {
        int i = (th + r * 256) * 4;
        float4 a = *(const float4*)&w[i];
        float4 b = *(const float4*)&h[i];
        s += a.x * b.x + a.y * b.y + a.z * b.z + a.w * b.w;
    }
    __shared__ float red[4];
    for (int off = 32; off; off >>= 1) s += __shfl_down(s, off);
    if ((th & 63) == 0) red[th >> 6] = s;
    __syncthreads();
    if (th == 0) {
        float tot = red[0] + red[1] + red[2] + red[3] + b1[o];
        hid[o] = tot > 0.f ? tot : 0.f;
    }
}

// ---------------- K3b: out = b2 + W2 . hid
__global__ void k_mlp2(const float* __restrict__ hid, const float* __restrict__ W2,
                       const float* __restrict__ b2, float* __restrict__ out) {
    int th = threadIdx.x;
    float s = hid[th] * W2[th];
    for (int off = 32; off; off >>= 1) s += __shfl_down(s, off);
    if (th == 0) out[0] = s + b2[0];
}

extern "C" void kernel_launch(void* const* d_in, const int* in_sizes, int n_in,
                              void* d_out, int out_size, void* d_ws, size_t ws_size,
                              hipStream_t stream) {
    const float* emb     = (const float*)d_in[0];
    const int*   lengths = (const int*)d_in[1];
    const float* W_ih    = (const float*)d_in[2];
    const float* W_hh    = (const float*)d_in[3];
    const float* b_ih    = (const float*)d_in[4];
    const float* b_hh    = (const float*)d_in[5];
    const float* W1      = (const float*)d_in[6];
    const float* b1      = (const float*)d_in[7];
    const float* W2      = (const float*)d_in[8];
    const float* b2      = (const float*)d_in[9];
    float* out = (float*)d_out;
    float* wsf = (float*)d_ws;

    const size_t tail = (size_t)V * H + V;  // h + hid (floats)
    int CT = 0;
    const int cts[5] = {2048, 1024, 512, 256, 128};
    for (int i = 0; i < 5; i++) {
        size_t need = ((size_t)V * cts[i] * G3 + tail) * sizeof(float);
        if (need <= ws_size) { CT = cts[i]; break; }
    }

    if (CT > 0) {
        float* xg  = wsf;
        float* hbf = wsf + (size_t)V * CT * G3;
        float* hid = hbf + (size_t)V * H;
        k_init<<<dim3((V * H + 255) / 256), dim3(256), 0, stream>>>(hbf);
        int nch = TMAX / CT;
        for (int c = 0; c < nch; c++) {
            k_gemm<<<dim3(CT / BT, 2, V), dim3(256), 0, stream>>>(emb, lengths, W_ih, b_ih, xg, c, CT);
            k_rec<<<dim3(V), dim3(64), 0, stream>>>(xg, lengths, W_hh, b_hh, hbf, c, CT);
        }
        k_mlp1<<<dim3(V), dim3(256), 0, stream>>>(hbf, W1, b1, hid);
        k_mlp2<<<dim3(1), dim3(64), 0, stream>>>(hid, W2, b2, out);
    } else {
        float* hbf = wsf;
        float* hid = hbf + (size_t)V * H;
        k_rec_fused<<<dim3(V), dim3(192), 0, stream>>>(emb, lengths, W_ih, b_ih, W_hh, b_hh, hbf);
        k_mlp1<<<dim3(V), dim3(256), 0, stream>>>(hbf, W1, b1, hid);
        k_mlp2<<<dim3(1), dim3(64), 0, stream>>>(hid, W2, b2, out);
    }
}

// Round 4
// 3020.417 us; speedup vs baseline: 1.6092x; 1.6092x over previous
//
#include <hip/hip_runtime.h>
#include <math.h>

#define V 64
#define TMAX 2048
#define ED 512
#define H 64
#define G3 192
#define BT 64          // t-rows per k_gemm block
#define CK 32          // k_rec LDS chunk (steps)

typedef const __attribute__((address_space(1))) void gvoid;
typedef __attribute__((address_space(3))) void lvoid;

// ---------------- K0: zero the persistent hidden state ----------------
__global__ void k_init(float* __restrict__ h) {
    int i = blockIdx.x * blockDim.x + threadIdx.x;
    if (i < V * H) h[i] = 0.f;
}

// ---------------- K1: xg[v, tloc, g] = b_ih[g] + sum_k emb[v,t,k] * W_ih[g,k]
// Block tile 64t x 192g, thread tile 8t x 6g (48 acc), K chunk 32.
// tq = th>>5 (uniform per half-wave) -> E LDS reads are broadcast; stores are
// half-wave contiguous. Plain register-staged LDS, padded rows (+4 floats).
__global__ __launch_bounds__(256, 1) void k_gemm(
    const float* __restrict__ emb, const int* __restrict__ lengths,
    const float* __restrict__ W_ih, const float* __restrict__ b_ih,
    float* __restrict__ xg, int c, int CT) {
    int v = blockIdx.y;
    int tile0 = blockIdx.x * BT;
    if (c * CT + tile0 >= lengths[v]) return;  // tile never read downstream

    __shared__ __align__(16) float Es[BT][36];
    __shared__ __align__(16) float Ws[G3][36];

    int th = threadIdx.x;
    int tq = th >> 5;     // 0..7  : t-rows tq*8 .. tq*8+7
    int gq = th & 31;     // 0..31 : g-rows gq*6 .. gq*6+5
    int srow = th >> 3;   // staging row 0..31
    int spos = th & 7;    // staging float4 slot

    const float* ebase = emb + ((size_t)v * TMAX + c * CT + tile0) * ED;

    float acc[8][6];
#pragma unroll
    for (int i = 0; i < 8; i++)
#pragma unroll
        for (int j = 0; j < 6; j++) acc[i][j] = 0.f;

    for (int kc = 0; kc < ED; kc += 32) {
        // stage E: 64 rows x 32 floats (2 float4 per thread)
#pragma unroll
        for (int r = 0; r < 2; r++) {
            int row = r * 32 + srow;
            float4 val = *(const float4*)&ebase[(size_t)row * ED + kc + spos * 4];
            *(float4*)&Es[row][spos * 4] = val;
        }
        // stage W: 192 rows x 32 floats (6 float4 per thread)
#pragma unroll
        for (int r = 0; r < 6; r++) {
            int row = r * 32 + srow;
            float4 val = *(const float4*)&W_ih[(size_t)row * ED + kc + spos * 4];
            *(float4*)&Ws[row][spos * 4] = val;
        }
        __syncthreads();
#pragma unroll
        for (int k4 = 0; k4 < 8; k4++) {
            float4 e[8], w[6];
#pragma unroll
            for (int i = 0; i < 8; i++) e[i] = *(float4*)&Es[tq * 8 + i][k4 * 4];
#pragma unroll
            for (int j = 0; j < 6; j++) w[j] = *(float4*)&Ws[gq * 6 + j][k4 * 4];
#pragma unroll
            for (int i = 0; i < 8; i++)
#pragma unroll
                for (int j = 0; j < 6; j++)
                    acc[i][j] += e[i].x * w[j].x + e[i].y * w[j].y +
                                 e[i].z * w[j].z + e[i].w * w[j].w;
        }
        __syncthreads();
    }

    float bj[6];
#pragma unroll
    for (int j = 0; j < 6; j++) bj[j] = b_ih[gq * 6 + j];

#pragma unroll
    for (int i = 0; i < 8; i++) {
        size_t ob = ((size_t)v * CT + tile0 + tq * 8 + i) * G3 + gq * 6;
#pragma unroll
        for (int j2 = 0; j2 < 3; j2++) {
            float2 s;
            s.x = acc[i][j2 * 2 + 0] + bj[j2 * 2 + 0];
            s.y = acc[i][j2 * 2 + 1] + bj[j2 * 2 + 1];
            *(float2*)&xg[ob + j2 * 2] = s;
        }
    }
}

// ---------------- K2: GRU recurrence, ONE WAVE per var, zero barriers.
// Lane i holds W_hh rows i (r), 64+i (z), 128+i (n) in 192 VGPRs.
// xg is staged into LDS in 32-step chunks with lane-contiguous global_load_lds
// (no staging VGPRs -> nothing to spill), double-buffered; one
// s_waitcnt vmcnt(0) per 32 steps. h exchanged through LDS (in-order DS).
__global__ __launch_bounds__(64, 1) void k_rec(
    const float* __restrict__ xg, const int* __restrict__ lengths,
    const float* __restrict__ W_hh, const float* __restrict__ b_hh,
    float* __restrict__ h, int c, int CT) {
    int v = blockIdx.x;
    int l = threadIdx.x;
    int rem = lengths[v] - c * CT;
    int tcnt = rem < 0 ? 0 : (rem > CT ? CT : rem);

    __shared__ __align__(16) float hs[H];
    __shared__ __align__(16) float xb[2][CK * G3];   // 2 x 24 KB

    float4 wr[16], wz[16], wn[16];
#pragma unroll
    for (int k4 = 0; k4 < 16; k4++) {
        wr[k4] = *(const float4*)&W_hh[(size_t)l * H + k4 * 4];
        wz[k4] = *(const float4*)&W_hh[(size_t)(64 + l) * H + k4 * 4];
        wn[k4] = *(const float4*)&W_hh[(size_t)(128 + l) * H + k4 * 4];
    }
    float br = b_hh[l], bz = b_hh[64 + l], bn = b_hh[128 + l];

    float hp = h[v * H + l];
    hs[l] = hp;

    const float* xgv = xg + (size_t)v * CT * G3;
    int nck = (tcnt + CK - 1) >> 5;   // chunks of 32 steps

    // prologue: load chunk 0 (24 x 1KB lane-contiguous)
    if (nck > 0) {
#pragma unroll
        for (int i = 0; i < 24; i++)
            __builtin_amdgcn_global_load_lds(
                (gvoid*)(xgv + i * 256 + l * 4), (lvoid*)&xb[0][i * 256], 16, 0, 0);
    }
    asm volatile("s_waitcnt vmcnt(0)" ::: "memory");

    const float LOG2E = 1.4426950408889634f;

    for (int ck = 0; ck < nck; ck++) {
        int buf = ck & 1;
        // prefetch next chunk into the other buffer (drained at loop bottom)
        if (ck + 1 < nck) {
            const float* src = xgv + (size_t)(ck + 1) * CK * G3;
#pragma unroll
            for (int i = 0; i < 24; i++)
                __builtin_amdgcn_global_load_lds(
                    (gvoid*)(src + i * 256 + l * 4), (lvoid*)&xb[buf ^ 1][i * 256], 16, 0, 0);
        }
        int t1 = tcnt - ck * CK;
        if (t1 > CK) t1 = CK;

        for (int t = 0; t < t1; t++) {
            const float* xrow = &xb[buf][t * G3];

            float ar0 = 0.f, ar1 = 0.f, ar2 = 0.f, ar3 = 0.f;
            float az0 = 0.f, az1 = 0.f, az2 = 0.f, az3 = 0.f;
            float an0 = 0.f, an1 = 0.f, an2 = 0.f, an3 = 0.f;
#pragma unroll
            for (int k4 = 0; k4 < 16; k4 += 4) {
                float4 h0 = *(float4*)&hs[k4 * 4];
                float4 h1 = *(float4*)&hs[k4 * 4 + 4];
                float4 h2 = *(float4*)&hs[k4 * 4 + 8];
                float4 h3 = *(float4*)&hs[k4 * 4 + 12];
                ar0 += wr[k4].x * h0.x + wr[k4].y * h0.y + wr[k4].z * h0.z + wr[k4].w * h0.w;
                ar1 += wr[k4+1].x * h1.x + wr[k4+1].y * h1.y + wr[k4+1].z * h1.z + wr[k4+1].w * h1.w;
                ar2 += wr[k4+2].x * h2.x + wr[k4+2].y * h2.y + wr[k4+2].z * h2.z + wr[k4+2].w * h2.w;
                ar3 += wr[k4+3].x * h3.x + wr[k4+3].y * h3.y + wr[k4+3].z * h3.z + wr[k4+3].w * h3.w;
                az0 += wz[k4].x * h0.x + wz[k4].y * h0.y + wz[k4].z * h0.z + wz[k4].w * h0.w;
                az1 += wz[k4+1].x * h1.x + wz[k4+1].y * h1.y + wz[k4+1].z * h1.z + wz[k4+1].w * h1.w;
                az2 += wz[k4+2].x * h2.x + wz[k4+2].y * h2.y + wz[k4+2].z * h2.z + wz[k4+2].w * h2.w;
                az3 += wz[k4+3].x * h3.x + wz[k4+3].y * h3.y + wz[k4+3].z * h3.z + wz[k4+3].w * h3.w;
                an0 += wn[k4].x * h0.x + wn[k4].y * h0.y + wn[k4].z * h0.z + wn[k4].w * h0.w;
                an1 += wn[k4+1].x * h1.x + wn[k4+1].y * h1.y + wn[k4+1].z * h1.z + wn[k4+1].w * h1.w;
                an2 += wn[k4+2].x * h2.x + wn[k4+2].y * h2.y + wn[k4+2].z * h2.z + wn[k4+2].w * h2.w;
                an3 += wn[k4+3].x * h3.x + wn[k4+3].y * h3.y + wn[k4+3].z * h3.z + wn[k4+3].w * h3.w;
            }
            float ar = ((ar0 + ar1) + (ar2 + ar3)) + br;
            float az = ((az0 + az1) + (az2 + az3)) + bz;
            float an = ((an0 + an1) + (an2 + an3)) + bn;

            float r = __builtin_amdgcn_rcpf(1.f + __builtin_amdgcn_exp2f(-LOG2E * (ar + xrow[l])));
            float z = __builtin_amdgcn_rcpf(1.f + __builtin_amdgcn_exp2f(-LOG2E * (az + xrow[64 + l])));
            float targ = xrow[128 + l] + r * an;
            float e2 = __builtin_amdgcn_exp2f(-2.f * LOG2E * fabsf(targ));
            float tn = (1.f - e2) * __builtin_amdgcn_rcpf(1.f + e2);
            tn = __builtin_copysignf(tn, targ);
            hp = tn + z * (hp - tn);

            __builtin_amdgcn_wave_barrier();
            hs[l] = hp;
            __builtin_amdgcn_wave_barrier();
        }
        // drain next chunk's loads before reading them (also fences reordering)
        asm volatile("s_waitcnt vmcnt(0)" ::: "memory");
    }
    h[v * H + l] = hp;
}

// ---------------- K2F: fully-fused fallback (tiny workspace). Slow but correct.
__global__ __launch_bounds__(192) void k_rec_fused(
    const float* __restrict__ emb, const int* __restrict__ lengths,
    const float* __restrict__ W_ih, const float* __restrict__ b_ih,
    const float* __restrict__ W_hh, const float* __restrict__ b_hh,
    float* __restrict__ h) {
    int v = blockIdx.x;
    int th = threadIdx.x;
    int len = lengths[v];

    __shared__ __align__(16) float hs[H];
    __shared__ __align__(16) float es[ED];
    __shared__ float znbuf[128];
    __shared__ float xnbuf[64];

    float4 w4[16];
#pragma unroll
    for (int k4 = 0; k4 < 16; k4++)
        w4[k4] = *(const float4*)&W_hh[(size_t)th * H + k4 * 4];
    float bhh = b_hh[th];
    float bih = b_ih[th];
    if (th < H) hs[th] = 0.f;
    const float* ev = emb + (size_t)v * TMAX * ED;
    const float* wrow = W_ih + (size_t)th * ED;

    for (int t = 0; t < len; t++) {
        __syncthreads();
        for (int i = th; i < 128; i += 192)
            *(float4*)&es[i * 4] = *(const float4*)&ev[(size_t)t * ED + i * 4];
        __syncthreads();
        float xgt = bih;
        for (int k4 = 0; k4 < 128; k4++) {
            float4 wv = *(const float4*)&wrow[k4 * 4];
            float4 e4 = *(float4*)&es[k4 * 4];
            xgt += wv.x * e4.x + wv.y * e4.y + wv.z * e4.z + wv.w * e4.w;
        }
        float hg = bhh;
#pragma unroll
        for (int k4 = 0; k4 < 16; k4++) {
            float4 h4 = *(float4*)&hs[k4 * 4];
            hg += w4[k4].x * h4.x + w4[k4].y * h4.y + w4[k4].z * h4.z + w4[k4].w * h4.w;
        }
        if (th >= H && th < 128) znbuf[th - H] = hg + xgt;
        if (th >= 128) { znbuf[th - H] = hg; xnbuf[th - 128] = xgt; }
        __syncthreads();
        if (th < H) {
            float r = 1.f / (1.f + expf(-(hg + xgt)));
            float z = 1.f / (1.f + expf(-znbuf[th]));
            float n = tanhf(xnbuf[th] + r * znbuf[64 + th]);
            float hold = hs[th];
            hs[th] = (1.f - z) * n + z * hold;
        }
    }
    __syncthreads();
    if (th < H) h[v * H + th] = hs[th];
}

// ---------------- K3a: hid[o] = relu(b1[o] + W1[o,:] . concat)
__global__ __launch_bounds__(256) void k_mlp1(
    const float* __restrict__ h, const float* __restrict__ W1,
    const float* __restrict__ b1, float* __restrict__ hid) {
    int o = blockIdx.x, th = threadIdx.x;
    const float* w = W1 + (size_t)o * (V * H);
    float s = 0.f;
#pragma unroll
    for (int r = 0; r < 4; r++) {
        int i = (th + r * 256) * 4;
        float4 a = *(const float4*)&w[i];
        float4 b = *(const float4*)&h[i];
        s += a.x * b.x + a.y * b.y + a.z * b.z + a.w * b.w;
    }
    __shared__ float red[4];
    for (int off = 32; off; off >>= 1) s += __shfl_down(s, off);
    if ((th & 63) == 0) red[th >> 6] = s;
    __syncthreads();
    if (th == 0) {
        float tot = red[0] + red[1] + red[2] + red[3] + b1[o];
        hid[o] = tot > 0.f ? tot : 0.f;
    }
}

// ---------------- K3b: out = b2 + W2 . hid
__global__ void k_mlp2(const float* __restrict__ hid, const float* __restrict__ W2,
                       const float* __restrict__ b2, float* __restrict__ out) {
    int th = threadIdx.x;
    float s = hid[th] * W2[th];
    for (int off = 32; off; off >>= 1) s += __shfl_down(s, off);
    if (th == 0) out[0] = s + b2[0];
}

extern "C" void kernel_launch(void* const* d_in, const int* in_sizes, int n_in,
                              void* d_out, int out_size, void* d_ws, size_t ws_size,
                              hipStream_t stream) {
    const float* emb     = (const float*)d_in[0];
    const int*   lengths = (const int*)d_in[1];
    const float* W_ih    = (const float*)d_in[2];
    const float* W_hh    = (const float*)d_in[3];
    const float* b_ih    = (const float*)d_in[4];
    const float* b_hh    = (const float*)d_in[5];
    const float* W1      = (const float*)d_in[6];
    const float* b1      = (const float*)d_in[7];
    const float* W2      = (const float*)d_in[8];
    const float* b2      = (const float*)d_in[9];
    float* out = (float*)d_out;
    float* wsf = (float*)d_ws;

    const size_t tail = (size_t)V * H + V;  // h + hid (floats)
    int CT = 0;
    const int cts[5] = {2048, 1024, 512, 256, 128};
    for (int i = 0; i < 5; i++) {
        size_t need = ((size_t)V * cts[i] * G3 + tail) * sizeof(float);
        if (need <= ws_size) { CT = cts[i]; break; }
    }

    if (CT > 0) {
        float* xg  = wsf;
        float* hbf = wsf + (size_t)V * CT * G3;
        float* hid = hbf + (size_t)V * H;
        k_init<<<dim3((V * H + 255) / 256), dim3(256), 0, stream>>>(hbf);
        int nch = TMAX / CT;
        for (int c = 0; c < nch; c++) {
            k_gemm<<<dim3(CT / BT, V), dim3(256), 0, stream>>>(emb, lengths, W_ih, b_ih, xg, c, CT);
            k_rec<<<dim3(V), dim3(64), 0, stream>>>(xg, lengths, W_hh, b_hh, hbf, c, CT);
        }
        k_mlp1<<<dim3(V), dim3(256), 0, stream>>>(hbf, W1, b1, hid);
        k_mlp2<<<dim3(1), dim3(64), 0, stream>>>(hid, W2, b2, out);
    } else {
        float* hbf = wsf;
        float* hid = hbf + (size_t)V * H;
        k_rec_fused<<<dim3(V), dim3(192), 0, stream>>>(emb, lengths, W_ih, b_ih, W_hh, b_hh, hbf);
        k_mlp1<<<dim3(V), dim3(256), 0, stream>>>(hbf, W1, b1, hid);
        k_mlp2<<<dim3(1), dim3(64), 0, stream>>>(hid, W2, b2, out);
    }
}